// Round 23
// baseline (41.459 us; speedup 1.0000x reference)
//
#include <hip/hip_runtime.h>

typedef float f32x4 __attribute__((ext_vector_type(4)));
typedef _Float16 f16x8 __attribute__((ext_vector_type(8)));
typedef __fp16 fp16x2 __attribute__((ext_vector_type(2)));

#define NEG_SLOPE 0.2f
#define MASK_EPS 1e-8f

// ---------------------------------------------------------------------------
// Kernel 0 (tiny): W (f32 [k][n]) -> wTf16 (f16 [n][k]). Separate launch so
// its output is visible to the fused kernel (R22's in-kernel W-prep raced
// with the wh path -> absmax 0.44; cross-launch ordering fixes it).
// ---------------------------------------------------------------------------
__global__ __launch_bounds__(256) void gat_prep_w(
    const float* __restrict__ W, _Float16* __restrict__ wTf16) {
  const int idx = blockIdx.x * 256 + threadIdx.x;
  const int k = idx >> 7, n = idx & 127;
  wTf16[n * 128 + k] = (_Float16)W[idx];
}

// ---------------------------------------------------------------------------
// Kernel 1 (fused, 1536 blocks x 512 thr, SEQUENTIAL heterogeneous):
//  bid in [0,1024): mask path — pack (adj>eps) into u16 half-words of
//    maskT (b = bid&31, ih16 = bid>>5); 16 coalesced row-loads per thread.
//  bid in [1024,1536): wh path — Wh = h @ W via f16 MFMA, 32 rows/block
//    (8 waves = 2 row-halves x 4 heads), blocked whT + scores epilogue.
// Sequential layout (NOT R10's bid&1 interleave): mask blocks dispatch
// first and keep their BW burst; wh blocks fill CUs as mask retires.
// Both paths independent (wh reads wTf16 from the PRIOR launch) -> no race.
// ---------------------------------------------------------------------------
__global__ __launch_bounds__(512, 4) void gat_prep_fused(
    const float* __restrict__ adj, unsigned short* __restrict__ maskT16,
    const _Float16* __restrict__ wTf16,
    const float* __restrict__ h, const float* __restrict__ a,
    _Float16* __restrict__ whT, float* __restrict__ sIT,
    float* __restrict__ sJT) {
  const int tid = threadIdx.x;
  const int bid = blockIdx.x;

  if (bid < 1024) {
    // ---- mask path ----
    const int b = bid & 31;
    const int ih16 = bid >> 5;         // 0..31
    const int j = tid;                 // 0..511
    const float* ap = adj + (size_t)b * 262144 + (size_t)ih16 * 16 * 512 + j;
    unsigned w = 0;
#pragma unroll
    for (int i = 0; i < 16; ++i)
      w |= (ap[(size_t)i * 512] > MASK_EPS ? 1u : 0u) << i;
    maskT16[((size_t)b * 512 + j) * 32 + ih16] = (unsigned short)w;
    return;
  }

  // ---- wh path: 32 rows/block; 8 waves = 2 row-halves x 4 heads ----
  const int wb = bid - 1024;           // 0..511
  const int w8 = tid >> 6;
  const int w = w8 & 3;                // head
  const int rh = w8 >> 2;              // row-half
  const int lane = tid & 63;
  const int nl = lane & 15;
  const int ig = lane >> 4;
  const int row0 = wb * 32 + rh * 16;
  const int bb = row0 >> 9;
  const int iloc = row0 & 511;

  const float* hP = h + (size_t)(row0 + nl) * 128 + ig * 8;
  const _Float16* wP0 = wTf16 + (size_t)(w * 32 + nl) * 128 + ig * 8;
  const _Float16* wP1 = wTf16 + (size_t)(w * 32 + 16 + nl) * 128 + ig * 8;

  f32x4 acc0 = {0.f, 0.f, 0.f, 0.f};
  f32x4 acc1 = {0.f, 0.f, 0.f, 0.f};

#pragma unroll
  for (int kt = 0; kt < 4; ++kt) {
    f32x4 ha = *(const f32x4*)(hP + kt * 32);
    f32x4 hb = *(const f32x4*)(hP + kt * 32 + 4);
    union { fp16x2 h2[4]; f16x8 v; } af;
    af.h2[0] = __builtin_amdgcn_cvt_pkrtz(ha.x, ha.y);
    af.h2[1] = __builtin_amdgcn_cvt_pkrtz(ha.z, ha.w);
    af.h2[2] = __builtin_amdgcn_cvt_pkrtz(hb.x, hb.y);
    af.h2[3] = __builtin_amdgcn_cvt_pkrtz(hb.z, hb.w);
    const f16x8 b0 = *(const f16x8*)(wP0 + kt * 32);
    const f16x8 b1 = *(const f16x8*)(wP1 + kt * 32);
    acc0 = __builtin_amdgcn_mfma_f32_16x16x32_f16(af.v, b0, acc0, 0, 0, 0);
    acc1 = __builtin_amdgcn_mfma_f32_16x16x32_f16(af.v, b1, acc1, 0, 0, 0);
  }

  const float avS0 = a[w * 64 + nl];
  const float avS1 = a[w * 64 + 16 + nl];
  const float avD0 = a[w * 64 + 32 + nl];
  const float avD1 = a[w * 64 + 48 + nl];

  float si[4], sj[4];
#pragma unroll
  for (int reg = 0; reg < 4; ++reg) {
    si[reg] = acc0[reg] * avS0 + acc1[reg] * avS1;
    sj[reg] = acc0[reg] * avD0 + acc1[reg] * avD1;
#pragma unroll
    for (int off = 1; off < 16; off <<= 1) {
      si[reg] += __shfl_xor(si[reg], off, 64);
      sj[reg] += __shfl_xor(sj[reg], off, 64);
    }
  }
  if (nl == 0) {
    const int base = bb * 2048 + w * 512 + iloc + ig * 4;
#pragma unroll
    for (int reg = 0; reg < 4; ++reg) {
      sIT[base + reg] = si[reg];
      sJT[base + reg] = sj[reg];
    }
  }

  // blocked whT write: [b][h][it=16][dd=32][i32=32]
  union { fp16x2 h2[2]; float2 f2; } p0, p1;
  p0.h2[0] = __builtin_amdgcn_cvt_pkrtz(acc0[0], acc0[1]);
  p0.h2[1] = __builtin_amdgcn_cvt_pkrtz(acc0[2], acc0[3]);
  p1.h2[0] = __builtin_amdgcn_cvt_pkrtz(acc1[0], acc1[1]);
  p1.h2[1] = __builtin_amdgcn_cvt_pkrtz(acc1[2], acc1[3]);
  const int i_base = iloc + ig * 4;
  const int it = i_base >> 5, i32 = i_base & 31;
  _Float16* wout = whT + (size_t)bb * 65536 + (size_t)w * 16384 + it * 1024 + i32;
  *(float2*)(wout + nl * 32)        = p0.f2;   // dd = nl
  *(float2*)(wout + (16 + nl) * 32) = p1.f2;   // dd = 16+nl
}

// ---------------------------------------------------------------------------
// Kernel 2: attention+aggregate (R21-proven, verbatim). 512 thr = 8 waves =
// 4 heads x 2 i-halves; j-tile 16; grid (32 b fast, 32 jt); launch_bounds
// (512,4) -> 64 VGPR spill-free, 8 waves/SIMD; blocked whT -> 1KB-coalesced
// B-frag loads; mask bits in registers; lrelu = fmaxf(e, 0.2e); mask folded
// before exp. i-halves merged via LDS + one barrier.
// ---------------------------------------------------------------------------
__global__ __launch_bounds__(512, 4) void gat_attn_kernel(
    const unsigned* __restrict__ maskT, const _Float16* __restrict__ whT,
    const float* __restrict__ sIT, const float* __restrict__ sJT,
    float* __restrict__ out) {
  __shared__ float ldsA[4][64][9];     // 9.2 KB: [hd][lane][acc0(4),acc1(4),l]

  const int tid = threadIdx.x;
  const int b = blockIdx.x;            // 0..31 (fast: same-b -> same XCD)
  const int j0 = blockIdx.y * 16;      // 32 tiles
  const int w8 = tid >> 6;             // 0..7
  const int hd = w8 & 3;               // head
  const int ih = w8 >> 2;              // i-half (256 i each)
  const int lane = tid & 63;
  const int nl = lane & 15;
  const int ig = lane >> 4;

  const float sj = sJT[b * 2048 + hd * 512 + j0 + nl];

  const unsigned* mP = maskT + ((size_t)b * 512 + j0 + nl) * 16 + ih * 8;
  uint4 mA = *(const uint4*)(mP);
  uint4 mB = *(const uint4*)(mP + 4);
  const unsigned mw[8] = {mA.x, mA.y, mA.z, mA.w, mB.x, mB.y, mB.z, mB.w};

  // blocked whT: [b][hd][it=16][dd=32][i32=32]; this half covers it = ih*8+st
  const _Float16* whP = whT + (size_t)b * 65536 + (size_t)hd * 16384
                        + (size_t)(ih * 8) * 1024 + nl * 32 + ig * 8;
  const float* siP = sIT + b * 2048 + hd * 512 + ih * 256 + ig * 8;

  f32x4 acc0 = {0.f, 0.f, 0.f, 0.f};
  f32x4 acc1 = {0.f, 0.f, 0.f, 0.f};
  float l = 0.f;

#pragma unroll
  for (int st = 0; st < 8; ++st) {     // 8 steps x 32 i = 256 i (half)
    f32x4 sA = *(const f32x4*)(siP + st * 32);
    f32x4 sB = *(const f32x4*)(siP + st * 32 + 4);
    const f16x8 bf0 = *(const f16x8*)(whP + st * 1024);        // dd = nl
    const f16x8 bf1 = *(const f16x8*)(whP + st * 1024 + 512);  // dd = 16+nl
    const unsigned bits = (mw[st] >> (ig * 8)) & 0xffu;

    float si[8] = {sA.x, sA.y, sA.z, sA.w, sB.x, sB.y, sB.z, sB.w};
    float p[8];
#pragma unroll
    for (int r = 0; r < 8; ++r) {
      float e = si[r] + sj;
      e = fmaxf(e, NEG_SLOPE * e);                 // lrelu: max(e, 0.2e)
      e = (bits & (1u << r)) ? e : -1e9f;          // mask before exp: exp(-1e9)=0
      p[r] = __expf(e);
    }
    l += ((p[0] + p[1]) + (p[2] + p[3])) + ((p[4] + p[5]) + (p[6] + p[7]));

    union { fp16x2 h2[4]; f16x8 v; } af;
#pragma unroll
    for (int q = 0; q < 4; ++q)
      af.h2[q] = __builtin_amdgcn_cvt_pkrtz(p[2 * q], p[2 * q + 1]);

    acc0 = __builtin_amdgcn_mfma_f32_16x16x32_f16(af.v, bf0, acc0, 0, 0, 0);
    acc1 = __builtin_amdgcn_mfma_f32_16x16x32_f16(af.v, bf1, acc1, 0, 0, 0);
  }

  // reduce l over the 4 ig-slices (within wave)
  l += __shfl_xor(l, 16, 64);
  l += __shfl_xor(l, 32, 64);

  // ---- merge the 2 i-halves via LDS (half-1 publishes, half-0 finishes) ----
  if (ih == 1) {
    float* dst = &ldsA[hd][lane][0];
#pragma unroll
    for (int q = 0; q < 4; ++q) { dst[q] = acc0[q]; dst[4 + q] = acc1[q]; }
    dst[8] = l;
  }
  __syncthreads();
  if (ih == 0) {
    const float* src = &ldsA[hd][lane][0];
#pragma unroll
    for (int q = 0; q < 4; ++q) { acc0[q] += src[q]; acc1[q] += src[4 + q]; }
    const float lt = l + src[8];

    // D layout: row(m=j_local) = 4*ig + reg, col(n=d_lo) = nl
    float* outB = out + ((size_t)b * 512 + j0) * 128 + hd * 32;
#pragma unroll
    for (int reg = 0; reg < 4; ++reg) {
      const int jr = 4 * ig + reg;
      const float rl = 1.0f / __shfl(lt, jr, 64);
      outB[(size_t)jr * 128 + nl]      = acc0[reg] * rl;
      outB[(size_t)jr * 128 + 16 + nl] = acc1[reg] * rl;
    }
  }
}

extern "C" void kernel_launch(void* const* d_in, const int* in_sizes, int n_in,
                              void* d_out, int out_size, void* d_ws, size_t ws_size,
                              hipStream_t stream) {
  const float* h = (const float*)d_in[0];     // (32, 512, 128)
  const float* adj = (const float*)d_in[1];   // (32, 512, 512)
  const float* W = (const float*)d_in[2];     // (128, 128)
  const float* a = (const float*)d_in[3];     // (4, 64)
  float* out = (float*)d_out;                 // (32, 512, 128)

  _Float16* whT = (_Float16*)d_ws;                      // 4 MB (blocked layout)
  float* sIT = (float*)(whT + (size_t)32 * 128 * 512);  // 256 KB
  float* sJT = sIT + (size_t)32 * 4 * 512;              // 256 KB
  unsigned* maskT = (unsigned*)(sJT + (size_t)32 * 4 * 512);      // 1 MB
  _Float16* wTf16 = (_Float16*)(maskT + (size_t)32 * 512 * 16);   // 32 KB

  gat_prep_w<<<dim3(64), dim3(256), 0, stream>>>(W, wTf16);
  gat_prep_fused<<<dim3(1536), dim3(512), 0, stream>>>(
      adj, (unsigned short*)maskT, wTf16, h, a, whT, sIT, sJT);
  gat_attn_kernel<<<dim3(32, 32), dim3(512), 0, stream>>>(maskT, whT, sIT, sJT, out);
}

// Round 24
// 38.275 us; speedup vs baseline: 1.0832x; 1.0832x over previous
//
#include <hip/hip_runtime.h>

typedef float f32x4 __attribute__((ext_vector_type(4)));
typedef _Float16 f16x8 __attribute__((ext_vector_type(8)));
typedef __fp16 fp16x2 __attribute__((ext_vector_type(2)));

#define NEG_SLOPE 0.2f
#define MASK_EPS 1e-8f

// ---------------------------------------------------------------------------
// Kernel 1: pack (adj > eps) into transposed bitmask, u16-half-word variant.
// Grid (32 b, 32 ih16) x 512 thr = 8192 waves = 8/SIMD. Block covers 16
// i-rows; thread = 1 j-column, 16 coalesced scalar loads, one u16 write.
// Blocks with ih16==0 also convert W -> wTf16 (f16 [n][k]). (R20/R21-proven)
// ---------------------------------------------------------------------------
__global__ __launch_bounds__(512) void gat_mask_kernel(
    const float* __restrict__ adj, unsigned short* __restrict__ maskT16,
    const float* __restrict__ W, _Float16* __restrict__ wTf16) {
  const int b = blockIdx.x;            // 0..31
  const int ih16 = blockIdx.y;         // 0..31: 16-i half-word index
  const int j = threadIdx.x;           // 0..511
  const float* ap = adj + (size_t)b * 262144 + (size_t)ih16 * 16 * 512 + j;
  unsigned w = 0;
#pragma unroll
  for (int i = 0; i < 16; ++i)
    w |= (ap[(size_t)i * 512] > MASK_EPS ? 1u : 0u) << i;
  maskT16[((size_t)b * 512 + j) * 32 + ih16] = (unsigned short)w;

  if (ih16 == 0) {                     // 32 blocks: W transpose+convert
    const int kq = j >> 7;             // 0..3
    const int n = j & 127;
    const int k = b * 4 + kq;
    wTf16[n * 128 + k] = (_Float16)W[k * 128 + n];
  }
}

// ---------------------------------------------------------------------------
// Kernel 2: Wh = h @ W via f16 MFMA. Zero LDS, zero barriers. (R7-proven)
// Epilogue writes whT in BLOCKED layout [b][h][it=16][dd=32][i32=32]
// (2KB contiguous 32x32 f16 tiles) so attn B-frag loads are coalesced.
// (R15-proven)
// ---------------------------------------------------------------------------
__global__ __launch_bounds__(256, 4) void gat_wh_mfma(
    const float* __restrict__ h, const _Float16* __restrict__ wTf16,
    const float* __restrict__ a, _Float16* __restrict__ whT,
    float* __restrict__ sIT, float* __restrict__ sJT) {
  const int tid = threadIdx.x;
  const int bid = blockIdx.x;          // 0..1023, 16 rows each
  const int w = tid >> 6;              // wave = head
  const int lane = tid & 63;
  const int nl = lane & 15;
  const int ig = lane >> 4;
  const int row0 = bid * 16;
  const int bb = row0 >> 9;
  const int iloc = row0 & 511;

  const float* hP = h + (size_t)(row0 + nl) * 128 + ig * 8;
  const _Float16* wP0 = wTf16 + (size_t)(w * 32 + nl) * 128 + ig * 8;
  const _Float16* wP1 = wTf16 + (size_t)(w * 32 + 16 + nl) * 128 + ig * 8;

  f32x4 acc0 = {0.f, 0.f, 0.f, 0.f};
  f32x4 acc1 = {0.f, 0.f, 0.f, 0.f};

#pragma unroll
  for (int kt = 0; kt < 4; ++kt) {
    f32x4 ha = *(const f32x4*)(hP + kt * 32);
    f32x4 hb = *(const f32x4*)(hP + kt * 32 + 4);
    union { fp16x2 h2[4]; f16x8 v; } af;
    af.h2[0] = __builtin_amdgcn_cvt_pkrtz(ha.x, ha.y);
    af.h2[1] = __builtin_amdgcn_cvt_pkrtz(ha.z, ha.w);
    af.h2[2] = __builtin_amdgcn_cvt_pkrtz(hb.x, hb.y);
    af.h2[3] = __builtin_amdgcn_cvt_pkrtz(hb.z, hb.w);
    const f16x8 b0 = *(const f16x8*)(wP0 + kt * 32);
    const f16x8 b1 = *(const f16x8*)(wP1 + kt * 32);
    acc0 = __builtin_amdgcn_mfma_f32_16x16x32_f16(af.v, b0, acc0, 0, 0, 0);
    acc1 = __builtin_amdgcn_mfma_f32_16x16x32_f16(af.v, b1, acc1, 0, 0, 0);
  }

  const float avS0 = a[w * 64 + nl];
  const float avS1 = a[w * 64 + 16 + nl];
  const float avD0 = a[w * 64 + 32 + nl];
  const float avD1 = a[w * 64 + 48 + nl];

  float si[4], sj[4];
#pragma unroll
  for (int reg = 0; reg < 4; ++reg) {
    si[reg] = acc0[reg] * avS0 + acc1[reg] * avS1;
    sj[reg] = acc0[reg] * avD0 + acc1[reg] * avD1;
#pragma unroll
    for (int off = 1; off < 16; off <<= 1) {
      si[reg] += __shfl_xor(si[reg], off, 64);
      sj[reg] += __shfl_xor(sj[reg], off, 64);
    }
  }
  if (nl == 0) {
    const int base = bb * 2048 + w * 512 + iloc + ig * 4;
#pragma unroll
    for (int reg = 0; reg < 4; ++reg) {
      sIT[base + reg] = si[reg];
      sJT[base + reg] = sj[reg];
    }
  }

  // blocked whT write: i_base = iloc + ig*4 (4 consecutive i in one tile)
  union { fp16x2 h2[2]; float2 f2; } p0, p1;
  p0.h2[0] = __builtin_amdgcn_cvt_pkrtz(acc0[0], acc0[1]);
  p0.h2[1] = __builtin_amdgcn_cvt_pkrtz(acc0[2], acc0[3]);
  p1.h2[0] = __builtin_amdgcn_cvt_pkrtz(acc1[0], acc1[1]);
  p1.h2[1] = __builtin_amdgcn_cvt_pkrtz(acc1[2], acc1[3]);
  const int i_base = iloc + ig * 4;
  const int it = i_base >> 5, i32 = i_base & 31;
  _Float16* wout = whT + (size_t)bb * 65536 + (size_t)w * 16384 + it * 1024 + i32;
  *(float2*)(wout + nl * 32)        = p0.f2;   // dd = nl
  *(float2*)(wout + (16 + nl) * 32) = p1.f2;   // dd = 16+nl
}

// ---------------------------------------------------------------------------
// Kernel 3: attention+aggregate (R21-proven). 512 thr = 8 waves = 4 heads x
// 2 i-halves; j-tile 16; grid (32 b fast, 32 jt); launch_bounds(512,4) ->
// 64 VGPR spill-free, 8 waves/SIMD; blocked whT -> 1KB-coalesced B-frag
// loads; mask bits in registers; lrelu = fmaxf(e, 0.2e); mask folded before
// exp (exp(-1e9) == 0 in f32). i-halves merged via LDS + one barrier.
// ---------------------------------------------------------------------------
__global__ __launch_bounds__(512, 4) void gat_attn_kernel(
    const unsigned* __restrict__ maskT, const _Float16* __restrict__ whT,
    const float* __restrict__ sIT, const float* __restrict__ sJT,
    float* __restrict__ out) {
  __shared__ float ldsA[4][64][9];     // 9.2 KB: [hd][lane][acc0(4),acc1(4),l]

  const int tid = threadIdx.x;
  const int b = blockIdx.x;            // 0..31 (fast: same-b -> same XCD)
  const int j0 = blockIdx.y * 16;      // 32 tiles
  const int w8 = tid >> 6;             // 0..7
  const int hd = w8 & 3;               // head
  const int ih = w8 >> 2;              // i-half (256 i each)
  const int lane = tid & 63;
  const int nl = lane & 15;
  const int ig = lane >> 4;

  const float sj = sJT[b * 2048 + hd * 512 + j0 + nl];

  const unsigned* mP = maskT + ((size_t)b * 512 + j0 + nl) * 16 + ih * 8;
  uint4 mA = *(const uint4*)(mP);
  uint4 mB = *(const uint4*)(mP + 4);
  const unsigned mw[8] = {mA.x, mA.y, mA.z, mA.w, mB.x, mB.y, mB.z, mB.w};

  // blocked whT: [b][hd][it=16][dd=32][i32=32]; this half covers it = ih*8+st
  const _Float16* whP = whT + (size_t)b * 65536 + (size_t)hd * 16384
                        + (size_t)(ih * 8) * 1024 + nl * 32 + ig * 8;
  const float* siP = sIT + b * 2048 + hd * 512 + ih * 256 + ig * 8;

  f32x4 acc0 = {0.f, 0.f, 0.f, 0.f};
  f32x4 acc1 = {0.f, 0.f, 0.f, 0.f};
  float l = 0.f;

#pragma unroll
  for (int st = 0; st < 8; ++st) {     // 8 steps x 32 i = 256 i (half)
    f32x4 sA = *(const f32x4*)(siP + st * 32);
    f32x4 sB = *(const f32x4*)(siP + st * 32 + 4);
    const f16x8 bf0 = *(const f16x8*)(whP + st * 1024);        // dd = nl
    const f16x8 bf1 = *(const f16x8*)(whP + st * 1024 + 512);  // dd = 16+nl
    const unsigned bits = (mw[st] >> (ig * 8)) & 0xffu;

    float si[8] = {sA.x, sA.y, sA.z, sA.w, sB.x, sB.y, sB.z, sB.w};
    float p[8];
#pragma unroll
    for (int r = 0; r < 8; ++r) {
      float e = si[r] + sj;
      e = fmaxf(e, NEG_SLOPE * e);                 // lrelu: max(e, 0.2e)
      e = (bits & (1u << r)) ? e : -1e9f;          // mask before exp: exp(-1e9)=0
      p[r] = __expf(e);
    }
    l += ((p[0] + p[1]) + (p[2] + p[3])) + ((p[4] + p[5]) + (p[6] + p[7]));

    union { fp16x2 h2[4]; f16x8 v; } af;
#pragma unroll
    for (int q = 0; q < 4; ++q)
      af.h2[q] = __builtin_amdgcn_cvt_pkrtz(p[2 * q], p[2 * q + 1]);

    acc0 = __builtin_amdgcn_mfma_f32_16x16x32_f16(af.v, bf0, acc0, 0, 0, 0);
    acc1 = __builtin_amdgcn_mfma_f32_16x16x32_f16(af.v, bf1, acc1, 0, 0, 0);
  }

  // reduce l over the 4 ig-slices (within wave)
  l += __shfl_xor(l, 16, 64);
  l += __shfl_xor(l, 32, 64);

  // ---- merge the 2 i-halves via LDS (half-1 publishes, half-0 finishes) ----
  if (ih == 1) {
    float* dst = &ldsA[hd][lane][0];
#pragma unroll
    for (int q = 0; q < 4; ++q) { dst[q] = acc0[q]; dst[4 + q] = acc1[q]; }
    dst[8] = l;
  }
  __syncthreads();
  if (ih == 0) {
    const float* src = &ldsA[hd][lane][0];
#pragma unroll
    for (int q = 0; q < 4; ++q) { acc0[q] += src[q]; acc1[q] += src[4 + q]; }
    const float lt = l + src[8];

    // D layout: row(m=j_local) = 4*ig + reg, col(n=d_lo) = nl
    float* outB = out + ((size_t)b * 512 + j0) * 128 + hd * 32;
#pragma unroll
    for (int reg = 0; reg < 4; ++reg) {
      const int jr = 4 * ig + reg;
      const float rl = 1.0f / __shfl(lt, jr, 64);
      outB[(size_t)jr * 128 + nl]      = acc0[reg] * rl;
      outB[(size_t)jr * 128 + 16 + nl] = acc1[reg] * rl;
    }
  }
}

extern "C" void kernel_launch(void* const* d_in, const int* in_sizes, int n_in,
                              void* d_out, int out_size, void* d_ws, size_t ws_size,
                              hipStream_t stream) {
  const float* h = (const float*)d_in[0];     // (32, 512, 128)
  const float* adj = (const float*)d_in[1];   // (32, 512, 512)
  const float* W = (const float*)d_in[2];     // (128, 128)
  const float* a = (const float*)d_in[3];     // (4, 64)
  float* out = (float*)d_out;                 // (32, 512, 128)

  _Float16* whT = (_Float16*)d_ws;                      // 4 MB (blocked layout)
  float* sIT = (float*)(whT + (size_t)32 * 128 * 512);  // 256 KB
  float* sJT = sIT + (size_t)32 * 4 * 512;              // 256 KB
  unsigned* maskT = (unsigned*)(sJT + (size_t)32 * 4 * 512);      // 1 MB
  _Float16* wTf16 = (_Float16*)(maskT + (size_t)32 * 512 * 16);   // 32 KB

  gat_mask_kernel<<<dim3(32, 32), dim3(512), 0, stream>>>(
      adj, (unsigned short*)maskT, W, wTf16);
  gat_wh_mfma<<<dim3(1024), dim3(256), 0, stream>>>(h, wTf16, a, whT, sIT, sJT);
  gat_attn_kernel<<<dim3(32, 32), dim3(512), 0, stream>>>(maskT, whT, sIT, sJT, out);
}